// Round 13
// baseline (143.029 us; speedup 1.0000x reference)
//
#include <hip/hip_runtime.h>
#include <hip/hip_bf16.h>

// GRUCell (B=262144, IN=2, H=50) + critic + actor-softmax.
// Inputs fp32, outputs fp32: d_out = h_new[B,50] | c[B,1] | pi[B,2].
// Extended-K MFMA: x[64]=[h(50),s(2),1,0...], W[64]=[w_hh,w_ih,bias,0...].
// R18 = R15 (best measured: 43.3us; one-shot 128-row 8-wave blocks, grid
// 2048, wlds copied from packed ws, one barrier, all loads at inst 0)
// + ONE change: hv (old h value in the gate math) is loaded from GLOBAL
// f32 into hv[4][4] registers up-front, replacing 16 per-lane
// ds_read_u16 + bf2f on the gate-math critical path. The rows are L1/L2
// -hot (this block just read them); per (reg,t) a quad's 16 lanes read
// 64B contiguous. Cuts per-wave LDS instruction count ~40%, shortens the
// gate dependency chain, and is exact-f32 (less rounding).
// Structural lessons banked: R16 (weights out of LDS) -7us, R17 (2-tile
// blocks) -14us, R13 (all-global) -29us => R15 structure is the optimum;
// only in-body micro-surgery from here.
// Discriminators: SQ_LDS_BANK_CONFLICT drops; FETCH stays ~27MB (hv hits
// cache; rise = refetch/spill tripwire); VGPR ~60.

#define BDIM 512

typedef __bf16 bf16x8 __attribute__((ext_vector_type(8)));
typedef float f32x4 __attribute__((ext_vector_type(4)));
typedef unsigned u32x4 __attribute__((ext_vector_type(4)));
typedef unsigned __attribute__((may_alias)) u32a;
typedef unsigned short __attribute__((may_alias)) u16a;

__device__ __forceinline__ unsigned short f2bf(float f) {   // pack kernel only
    union { float f; unsigned u; } x; x.f = f;
    unsigned r = x.u + 0x7fffu + ((x.u >> 16) & 1u);
    return (unsigned short)(r >> 16);
}
__device__ __forceinline__ unsigned packbf(float a, float b) {  // v_cvt_pk_bf16_f32
    union { __hip_bfloat162 h; unsigned u; } c;
    c.h = __float22bfloat162_rn(make_float2(a, b));
    return c.u;
}
__device__ __forceinline__ bf16x8 ldsfrag(const unsigned short* p) {
    bf16x8 v; __builtin_memcpy(&v, p, 16); return v;   // alias-safe b128 read
}

// DPP rotate-add within each 16-lane row: VALU pipe, no LDS.
template <int CTRL>
__device__ __forceinline__ float dpp_add(float v) {
    int s = __builtin_bit_cast(int, v);
    int r = __builtin_amdgcn_update_dpp(s, s, CTRL, 0xf, 0xf, false);
    return v + __builtin_bit_cast(float, r);
}
__device__ __forceinline__ float row16_sum(float v) {
    v = dpp_add<0x128>(v);   // + ror 8
    v = dpp_add<0x124>(v);   // + ror 4
    v = dpp_add<0x122>(v);   // + ror 2
    v = dpp_add<0x121>(v);   // + ror 1 -> every lane has full 16-lane sum
    return v;
}

// ---- K1: pack weight fragments into ws (exact wlds layout).
// e = (g<<9)|(t<<7)|(ks<<6)|lane ; ws[e] = 16B (8 bf16, k ascending).
__global__ __launch_bounds__(256, 1) void pack_w(
    const float* __restrict__ w_ih, const float* __restrict__ w_hh,
    const float* __restrict__ b_ih, const float* __restrict__ b_hh,
    u32x4* __restrict__ ws)
{
    int e = blockIdx.x * 256 + threadIdx.x;
    if (e >= 1536) return;
    int ln = e & 63;
    int ks = (e >> 6) & 1;
    int t  = (e >> 7) & 3;
    int g  = e >> 9;
    int n  = t * 16 + (ln & 15);
    int kbase = ks * 32 + (ln >> 4) * 8;
    unsigned short vals[8];
    if (n < 50) {
        int r = g * 50 + n;
        #pragma unroll
        for (int i = 0; i < 8; ++i) {
            int k = kbase + i;
            float v = 0.f;
            if (k < 50)       v = w_hh[r * 50 + k];
            else if (k == 50) v = (g < 2) ? w_ih[r * 2 + 0] : 0.f;
            else if (k == 51) v = (g < 2) ? w_ih[r * 2 + 1] : 0.f;
            else if (k == 52) {
                v = b_hh[r];                 // n-gate: b_hh only
                if (g < 2) v += b_ih[r];     // r/z: both biases fused
            }
            vals[i] = f2bf(v);
        }
    } else {
        #pragma unroll
        for (int i = 0; i < 8; ++i) vals[i] = 0;
    }
    u32x4 o;
    #pragma unroll
    for (int i = 0; i < 4; ++i)
        o[i] = (unsigned)vals[2 * i] | ((unsigned)vals[2 * i + 1] << 16);
    ws[e] = o;
}

__global__ __launch_bounds__(BDIM, 4) void gru_fused(
    const float* __restrict__ s,
    const float* __restrict__ h,
    const float* __restrict__ w_ih,
    const float* __restrict__ actor_w,
    const float* __restrict__ actor_b,
    const float* __restrict__ critic_w,
    const float* __restrict__ critic_b,
    const float* __restrict__ b_ih,
    const u32x4* __restrict__ ws,
    float* __restrict__ out,
    int Btot, int nTiles)
{
    // bf16 x-tile: 128 rows x 72 shorts (144B stride); shorts 0..49 h,
    // 50..51 s, 52 = 1.0, 53..63 = 0, 64..71 pad.
    __shared__ __align__(16) unsigned short xlds[128 * 72];   // 18432 B
    // weight B-fragments: [g(3)][t(4)][ks(2)][lane(64)][8 bf16]
    __shared__ __align__(16) unsigned short wlds[1536 * 8];   // 24576 B

    const int tid  = threadIdx.x;
    const int wave = tid >> 6;           // 0..7
    const int lane = tid & 63;
    const int c16  = lane & 15;
    const int quad = lane >> 4;
    const int R    = wave * 16;          // this wave's private 16-row band

    u32a* xlds32 = (u32a*)xlds;

    const int bt = blockIdx.x;
    const int rowbase = bt * 128;
    const float2* h2 = (const float2*)h;
    const float2* s2 = (const float2*)s;

    // ---- FIRST: issue this wave's h/s loads (the block's 25.6KB of reads
    // all go in flight at block start; init below hides the latency) ----
    float2 pf[7];
    {
        long long hb = (long long)(rowbase + R) * 25;
        #pragma unroll
        for (int j = 0; j < 6; ++j) pf[j] = h2[hb + lane + j * 64];
        if (lane < 16)      pf[6] = h2[hb + 384 + lane];
        else if (lane < 32) pf[6] = s2[rowbase + R + lane - 16];
    }

    // ---- init: wlds = coalesced 16B copy from prepacked ws (L2-hot) ----
    u32x4* wlds16 = (u32x4*)wlds;
    for (int i = tid; i < 1536; i += BDIM)
        wlds16[i] = ws[i];

    // ---- init: const zone of OWN band (rows R..R+15, dwords 26..35):
    // short 52 = 1.0 bf16, 53..71 = 0. ----
    for (int i = lane; i < 160; i += 64) {
        int row = R + i / 10, dk = 26 + i % 10;
        xlds32[row * 36 + dk] = (i % 10 == 0) ? 0x00003f80u : 0u;
    }

    // ---- hoisted per-lane constants (loop-invariant global reads) ----
    float wi0[4], wi1[4], bi[4], aw0[4], aw1[4], awc[4];
    #pragma unroll
    for (int t = 0; t < 4; ++t) {
        int j = t * 16 + c16;
        bool ok = (j < 50);
        wi0[t] = ok ? w_ih[(100 + j) * 2 + 0] : 0.f;
        wi1[t] = ok ? w_ih[(100 + j) * 2 + 1] : 0.f;
        bi[t]  = ok ? b_ih[100 + j]           : 0.f;
        aw0[t] = ok ? actor_w[j]              : 0.f;
        aw1[t] = ok ? actor_w[50 + j]         : 0.f;
        awc[t] = ok ? critic_w[j]             : 0.f;
    }
    const float ab0 = actor_b[0], ab1 = actor_b[1], cb = critic_b[0];

    __syncthreads();   // wlds visible to all waves

    // ---- stage own band: regs -> LDS (alias-safe u32a writes) ----
    #pragma unroll
    for (int j = 0; j < 6; ++j) {
        int d = lane + j * 64;
        int r = d / 25, dk = d - r * 25;
        xlds32[(R + r) * 36 + dk] = packbf(pf[j].x, pf[j].y);
    }
    if (lane < 16)
        xlds32[(R + 15) * 36 + 9 + lane] = packbf(pf[6].x, pf[6].y);
    else if (lane < 32)
        xlds32[(R + lane - 16) * 36 + 25] = packbf(pf[6].x, pf[6].y);

    // compiler fence: staging writes ordered before all following reads
    asm volatile("" ::: "memory");

    // ---- s rows for gate math (L2-hot, 16-lane broadcast) ----
    float2 srow[4];
    #pragma unroll
    for (int reg = 0; reg < 4; ++reg)
        srow[reg] = s2[rowbase + R + quad * 4 + reg];

    // ---- hv: old-h values direct from GLOBAL f32 (L1/L2-hot: this block
    // just read these rows). Replaces 16 ds_read_u16 + bf2f on the gate
    // chain; per (reg,t) a quad's 16 lanes read 64B contiguous. Issued
    // here so latency hides under the A-frag reads + MFMAs. ----
    float hv[4][4];
    #pragma unroll
    for (int reg = 0; reg < 4; ++reg) {
        const float* hr2 = h + (rowbase + R + quad * 4 + reg) * 50;
        #pragma unroll
        for (int t = 0; t < 4; ++t) {
            int j = t * 16 + c16;
            hv[reg][t] = (j < 50) ? hr2[j] : 0.f;
        }
    }

    // ---- A fragments (own band, alias-safe reads) ----
    const unsigned short* arow = &xlds[(R + c16) * 72 + quad * 8];
    bf16x8 a0 = ldsfrag(arow);        // k 0..31
    bf16x8 a1 = ldsfrag(arow + 32);   // k 32..63

    float* ob = out + (long long)rowbase * 50;   // 32-bit lane offsets
    float* oc = out + (long long)Btot * 50;
    float2* opi = (float2*)(out + (long long)Btot * 51);

    // ---- per-t: 6 MFMAs then gate math ----
    float hn_r[4][4];
    #pragma unroll
    for (int t = 0; t < 4; ++t) {
        f32x4 ar = {0.f,0.f,0.f,0.f}, az = ar, an = ar;
        const int tb = (t * 128 + lane) * 8;   // shorts; ks +512, g +4096
        bf16x8 br0 = ldsfrag(&wlds[tb]);
        bf16x8 br1 = ldsfrag(&wlds[tb + 512]);
        bf16x8 bz0 = ldsfrag(&wlds[tb + 4096]);
        bf16x8 bz1 = ldsfrag(&wlds[tb + 4608]);
        bf16x8 bn0 = ldsfrag(&wlds[tb + 8192]);
        bf16x8 bn1 = ldsfrag(&wlds[tb + 8704]);
        ar = __builtin_amdgcn_mfma_f32_16x16x32_bf16(a0, br0, ar, 0, 0, 0);
        ar = __builtin_amdgcn_mfma_f32_16x16x32_bf16(a1, br1, ar, 0, 0, 0);
        az = __builtin_amdgcn_mfma_f32_16x16x32_bf16(a0, bz0, az, 0, 0, 0);
        az = __builtin_amdgcn_mfma_f32_16x16x32_bf16(a1, bz1, az, 0, 0, 0);
        an = __builtin_amdgcn_mfma_f32_16x16x32_bf16(a0, bn0, an, 0, 0, 0);
        an = __builtin_amdgcn_mfma_f32_16x16x32_bf16(a1, bn1, an, 0, 0, 0);

        int j = t * 16 + c16;
        #pragma unroll
        for (int reg = 0; reg < 4; ++reg) {
            int lr = R + quad * 4 + reg;       // C/D: row = quad*4+reg
            float inn = fmaf(srow[reg].y, wi1[t],
                        fmaf(srow[reg].x, wi0[t], bi[t]));
            float rg = __builtin_amdgcn_rcpf(1.f + __expf(-ar[reg]));
            float zg = __builtin_amdgcn_rcpf(1.f + __expf(-az[reg]));
            float x = inn + rg * an[reg];
            float e2 = __expf(2.f * x);   // saturates: ng -> +-1, no NaN
            float ng = 1.f - 2.f * __builtin_amdgcn_rcpf(e2 + 1.f);
            float hnew = fmaf(zg, hv[reg][t] - ng, ng);
            hn_r[reg][t] = (j < 50) ? hnew : 0.f;
            if (j < 50) ob[lr * 50 + j] = hnew;
        }
    }

    // ---- heads from registers: DPP row_ror rotate-reduce (VALU pipe) ----
    float sum0[4], sum1[4], sumc[4];
    #pragma unroll
    for (int reg = 0; reg < 4; ++reg) {
        float p0 = 0.f, p1 = 0.f, pc = 0.f;
        #pragma unroll
        for (int t = 0; t < 4; ++t) {
            p0 = fmaf(hn_r[reg][t], aw0[t], p0);
            p1 = fmaf(hn_r[reg][t], aw1[t], p1);
            pc = fmaf(hn_r[reg][t], awc[t], pc);
        }
        sum0[reg] = row16_sum(p0);
        sum1[reg] = row16_sum(p1);
        sumc[reg] = row16_sum(pc);
    }
    if (c16 < 4) {   // lane c16==reg writes row quad*4+c16
        float A0 = (c16 == 0) ? sum0[0] : (c16 == 1) ? sum0[1]
                 : (c16 == 2) ? sum0[2] : sum0[3];
        float A1 = (c16 == 0) ? sum1[0] : (c16 == 1) ? sum1[1]
                 : (c16 == 2) ? sum1[2] : sum1[3];
        float C  = (c16 == 0) ? sumc[0] : (c16 == 1) ? sumc[1]
                 : (c16 == 2) ? sumc[2] : sumc[3];
        int gr = rowbase + R + quad * 4 + c16;
        oc[gr] = C + cb;
        A0 += ab0; A1 += ab1;
        float m = fmaxf(A0, A1);
        float e0 = __expf(A0 - m), e1 = __expf(A1 - m);
        float inv = 1.f / (e0 + e1);
        float2 pv; pv.x = e0 * inv; pv.y = e1 * inv;
        opi[gr] = pv;
    }
}

extern "C" void kernel_launch(void* const* d_in, const int* in_sizes, int n_in,
                              void* d_out, int out_size, void* d_ws, size_t ws_size,
                              hipStream_t stream) {
    const float* s        = (const float*)d_in[0];
    const float* h        = (const float*)d_in[1];
    const float* w_ih     = (const float*)d_in[2];
    const float* w_hh     = (const float*)d_in[3];
    const float* b_ih     = (const float*)d_in[4];
    const float* b_hh     = (const float*)d_in[5];
    const float* actor_w  = (const float*)d_in[6];
    const float* actor_b  = (const float*)d_in[7];
    const float* critic_w = (const float*)d_in[8];
    const float* critic_b = (const float*)d_in[9];
    float* out = (float*)d_out;

    int Btot = in_sizes[1] / 50;          // 262144
    int nTiles = Btot / 128;              // 2048 (exact)

    u32x4* ws = (u32x4*)d_ws;             // needs 1536*16 = 24576 B

    pack_w<<<6, 256, 0, stream>>>(w_ih, w_hh, b_ih, b_hh, ws);
    gru_fused<<<nTiles, BDIM, 0, stream>>>(s, h, w_ih, actor_w, actor_b,
                                           critic_w, critic_b, b_ih,
                                           (const u32x4*)ws, out, Btot, nTiles);
}

// Round 14
// 140.228 us; speedup vs baseline: 1.0200x; 1.0200x over previous
//
#include <hip/hip_runtime.h>
#include <hip/hip_bf16.h>

// GRUCell (B=262144, IN=2, H=50) + critic + actor-softmax.
// Inputs fp32, outputs fp32: d_out = h_new[B,50] | c[B,1] | pi[B,2].
// Extended-K MFMA: x[64]=[h(50),s(2),1,0...], W[64]=[w_hh,w_ih,bias,0...].
// R19 = R15 (best: 43.3us; one-shot 128-row 8-wave blocks, grid 2048,
// wlds copied from packed ws, one barrier, loads at inst 0, hv from LDS)
// + ONE change: xlds row stride 72 -> 56 shorts (112B = 7x16B, b128
// alignment preserved). Rationale: R15's LDS = 43008B -> 3 blocks/CU
// (163840/43008), 2048B over the 4-block line. The k=56..63 slice of the
// A fragment multiplies weight columns that are IDENTICALLY ZERO (pack
// zeroes k>52), so quad-3 a1 may read garbage -- the row needn't exist
// past k=55. Row = 25 h-dwords | s-pair | (1.0,0) | (0,0); quad-3 a1
// reads 16B into the next row (benign, weight-masked); 8-short tail pad
// for row 127. xlds 18432 -> 14352B; block LDS 38928 <= 40960 ->
// 4 blocks/CU, 32-wave cap. R18 lesson banked: hv-from-global is neutral
// with +3MB FETCH -> keep hv from LDS.
// Discriminators: LDS_Block_Size ~38928; occupancy 36 -> 45-55; dur
// ~35-39 if LDS-capped residency binds, flat if not (kills the last
// capacity lever -> structural stall floor).

#define BDIM 512

typedef __bf16 bf16x8 __attribute__((ext_vector_type(8)));
typedef float f32x4 __attribute__((ext_vector_type(4)));
typedef unsigned u32x4 __attribute__((ext_vector_type(4)));
typedef unsigned __attribute__((may_alias)) u32a;
typedef unsigned short __attribute__((may_alias)) u16a;

__device__ __forceinline__ float bf2f(unsigned short u) {
    union { unsigned u; float f; } x; x.u = ((unsigned)u) << 16; return x.f;
}
__device__ __forceinline__ unsigned short f2bf(float f) {   // pack kernel only
    union { float f; unsigned u; } x; x.f = f;
    unsigned r = x.u + 0x7fffu + ((x.u >> 16) & 1u);
    return (unsigned short)(r >> 16);
}
__device__ __forceinline__ unsigned packbf(float a, float b) {  // v_cvt_pk_bf16_f32
    union { __hip_bfloat162 h; unsigned u; } c;
    c.h = __float22bfloat162_rn(make_float2(a, b));
    return c.u;
}
__device__ __forceinline__ bf16x8 ldsfrag(const unsigned short* p) {
    bf16x8 v; __builtin_memcpy(&v, p, 16); return v;   // alias-safe b128 read
}

// DPP rotate-add within each 16-lane row: VALU pipe, no LDS.
template <int CTRL>
__device__ __forceinline__ float dpp_add(float v) {
    int s = __builtin_bit_cast(int, v);
    int r = __builtin_amdgcn_update_dpp(s, s, CTRL, 0xf, 0xf, false);
    return v + __builtin_bit_cast(float, r);
}
__device__ __forceinline__ float row16_sum(float v) {
    v = dpp_add<0x128>(v);   // + ror 8
    v = dpp_add<0x124>(v);   // + ror 4
    v = dpp_add<0x122>(v);   // + ror 2
    v = dpp_add<0x121>(v);   // + ror 1 -> every lane has full 16-lane sum
    return v;
}

// ---- K1: pack weight fragments into ws (exact wlds layout).
// e = (g<<9)|(t<<7)|(ks<<6)|lane ; ws[e] = 16B (8 bf16, k ascending).
__global__ __launch_bounds__(256, 1) void pack_w(
    const float* __restrict__ w_ih, const float* __restrict__ w_hh,
    const float* __restrict__ b_ih, const float* __restrict__ b_hh,
    u32x4* __restrict__ ws)
{
    int e = blockIdx.x * 256 + threadIdx.x;
    if (e >= 1536) return;
    int ln = e & 63;
    int ks = (e >> 6) & 1;
    int t  = (e >> 7) & 3;
    int g  = e >> 9;
    int n  = t * 16 + (ln & 15);
    int kbase = ks * 32 + (ln >> 4) * 8;
    unsigned short vals[8];
    if (n < 50) {
        int r = g * 50 + n;
        #pragma unroll
        for (int i = 0; i < 8; ++i) {
            int k = kbase + i;
            float v = 0.f;
            if (k < 50)       v = w_hh[r * 50 + k];
            else if (k == 50) v = (g < 2) ? w_ih[r * 2 + 0] : 0.f;
            else if (k == 51) v = (g < 2) ? w_ih[r * 2 + 1] : 0.f;
            else if (k == 52) {
                v = b_hh[r];                 // n-gate: b_hh only
                if (g < 2) v += b_ih[r];     // r/z: both biases fused
            }
            vals[i] = f2bf(v);
        }
    } else {
        #pragma unroll
        for (int i = 0; i < 8; ++i) vals[i] = 0;
    }
    u32x4 o;
    #pragma unroll
    for (int i = 0; i < 4; ++i)
        o[i] = (unsigned)vals[2 * i] | ((unsigned)vals[2 * i + 1] << 16);
    ws[e] = o;
}

__global__ __launch_bounds__(BDIM, 4) void gru_fused(
    const float* __restrict__ s,
    const float* __restrict__ h,
    const float* __restrict__ w_ih,
    const float* __restrict__ actor_w,
    const float* __restrict__ actor_b,
    const float* __restrict__ critic_w,
    const float* __restrict__ critic_b,
    const float* __restrict__ b_ih,
    const u32x4* __restrict__ ws,
    float* __restrict__ out,
    int Btot, int nTiles)
{
    // bf16 x-tile: 128 rows x 56 shorts (112B stride, 7x16B): shorts
    // 0..49 h, 50..51 s, 52 = 1.0, 53..55 = 0. +8-short tail pad so row
    // 127's quad-3 a1 over-read stays in-bounds (its product is zero
    // because pack_w zeroes weight k=56..63).
    __shared__ __align__(16) unsigned short xlds[128 * 56 + 8];   // 14352 B
    // weight B-fragments: [g(3)][t(4)][ks(2)][lane(64)][8 bf16]
    __shared__ __align__(16) unsigned short wlds[1536 * 8];       // 24576 B

    const int tid  = threadIdx.x;
    const int wave = tid >> 6;           // 0..7
    const int lane = tid & 63;
    const int c16  = lane & 15;
    const int quad = lane >> 4;
    const int R    = wave * 16;          // this wave's private 16-row band

    u32a* xlds32 = (u32a*)xlds;

    const int bt = blockIdx.x;
    const int rowbase = bt * 128;
    const float2* h2 = (const float2*)h;
    const float2* s2 = (const float2*)s;

    // ---- FIRST: issue this wave's h/s loads (the block's 25.6KB of reads
    // all go in flight at block start; init below hides the latency) ----
    float2 pf[7];
    {
        long long hb = (long long)(rowbase + R) * 25;
        #pragma unroll
        for (int j = 0; j < 6; ++j) pf[j] = h2[hb + lane + j * 64];
        if (lane < 16)      pf[6] = h2[hb + 384 + lane];
        else if (lane < 32) pf[6] = s2[rowbase + R + lane - 16];
    }

    // ---- init: wlds = coalesced 16B copy from prepacked ws (L2-hot) ----
    u32x4* wlds16 = (u32x4*)wlds;
    for (int i = tid; i < 1536; i += BDIM)
        wlds16[i] = ws[i];

    // ---- init: const zone of OWN band (rows R..R+15, dwords 26..27):
    // dword 26 = (1.0bf16, 0), dword 27 = (0,0). lane<32: one dword each.
    if (lane < 32) {
        int row = R + (lane >> 1), dk = 26 + (lane & 1);
        xlds32[row * 28 + dk] = (lane & 1) ? 0u : 0x00003f80u;
    }

    // ---- hoisted per-lane constants (loop-invariant global reads) ----
    float wi0[4], wi1[4], bi[4], aw0[4], aw1[4], awc[4];
    #pragma unroll
    for (int t = 0; t < 4; ++t) {
        int j = t * 16 + c16;
        bool ok = (j < 50);
        wi0[t] = ok ? w_ih[(100 + j) * 2 + 0] : 0.f;
        wi1[t] = ok ? w_ih[(100 + j) * 2 + 1] : 0.f;
        bi[t]  = ok ? b_ih[100 + j]           : 0.f;
        aw0[t] = ok ? actor_w[j]              : 0.f;
        aw1[t] = ok ? actor_w[50 + j]         : 0.f;
        awc[t] = ok ? critic_w[j]             : 0.f;
    }
    const float ab0 = actor_b[0], ab1 = actor_b[1], cb = critic_b[0];

    __syncthreads();   // wlds visible to all waves

    // ---- stage own band: regs -> LDS (alias-safe u32a writes) ----
    #pragma unroll
    for (int j = 0; j < 6; ++j) {
        int d = lane + j * 64;
        int r = d / 25, dk = d - r * 25;
        xlds32[(R + r) * 28 + dk] = packbf(pf[j].x, pf[j].y);
    }
    if (lane < 16)
        xlds32[(R + 15) * 28 + 9 + lane] = packbf(pf[6].x, pf[6].y);
    else if (lane < 32)
        xlds32[(R + lane - 16) * 28 + 25] = packbf(pf[6].x, pf[6].y);

    // compiler fence: staging writes ordered before all following reads
    asm volatile("" ::: "memory");

    // ---- s rows for gate math (L2-hot, 16-lane broadcast) ----
    float2 srow[4];
    #pragma unroll
    for (int reg = 0; reg < 4; ++reg)
        srow[reg] = s2[rowbase + R + quad * 4 + reg];

    // ---- A fragments (own band). a1 quad-3 reads 16B past the row --
    // harmless: weight k=56..63 is zero, product vanishes. ----
    const unsigned short* arow = &xlds[(R + c16) * 56 + quad * 8];
    bf16x8 a0 = ldsfrag(arow);        // k 0..31
    bf16x8 a1 = ldsfrag(arow + 32);   // k 32..63 (quad3: garbage, masked)

    float* ob = out + (long long)rowbase * 50;   // 32-bit lane offsets
    float* oc = out + (long long)Btot * 50;
    float2* opi = (float2*)(out + (long long)Btot * 51);

    // ---- per-t: 6 MFMAs then gate math ----
    float hn_r[4][4];
    #pragma unroll
    for (int t = 0; t < 4; ++t) {
        f32x4 ar = {0.f,0.f,0.f,0.f}, az = ar, an = ar;
        const int tb = (t * 128 + lane) * 8;   // shorts; ks +512, g +4096
        bf16x8 br0 = ldsfrag(&wlds[tb]);
        bf16x8 br1 = ldsfrag(&wlds[tb + 512]);
        bf16x8 bz0 = ldsfrag(&wlds[tb + 4096]);
        bf16x8 bz1 = ldsfrag(&wlds[tb + 4608]);
        bf16x8 bn0 = ldsfrag(&wlds[tb + 8192]);
        bf16x8 bn1 = ldsfrag(&wlds[tb + 8704]);
        ar = __builtin_amdgcn_mfma_f32_16x16x32_bf16(a0, br0, ar, 0, 0, 0);
        ar = __builtin_amdgcn_mfma_f32_16x16x32_bf16(a1, br1, ar, 0, 0, 0);
        az = __builtin_amdgcn_mfma_f32_16x16x32_bf16(a0, bz0, az, 0, 0, 0);
        az = __builtin_amdgcn_mfma_f32_16x16x32_bf16(a1, bz1, az, 0, 0, 0);
        an = __builtin_amdgcn_mfma_f32_16x16x32_bf16(a0, bn0, an, 0, 0, 0);
        an = __builtin_amdgcn_mfma_f32_16x16x32_bf16(a1, bn1, an, 0, 0, 0);

        int j = t * 16 + c16;
        #pragma unroll
        for (int reg = 0; reg < 4; ++reg) {
            int lr = R + quad * 4 + reg;       // C/D: row = quad*4+reg
            float inn = fmaf(srow[reg].y, wi1[t],
                        fmaf(srow[reg].x, wi0[t], bi[t]));
            float rg = __builtin_amdgcn_rcpf(1.f + __expf(-ar[reg]));
            float zg = __builtin_amdgcn_rcpf(1.f + __expf(-az[reg]));
            float x = inn + rg * an[reg];
            float e2 = __expf(2.f * x);   // saturates: ng -> +-1, no NaN
            float ng = 1.f - 2.f * __builtin_amdgcn_rcpf(e2 + 1.f);
            float hv = bf2f(((const u16a*)xlds)[lr * 56 + j]);
            float hnew = fmaf(zg, hv - ng, ng);
            hn_r[reg][t] = (j < 50) ? hnew : 0.f;
            if (j < 50) ob[lr * 50 + j] = hnew;
        }
    }

    // ---- heads from registers: DPP row_ror rotate-reduce (VALU pipe) ----
    float sum0[4], sum1[4], sumc[4];
    #pragma unroll
    for (int reg = 0; reg < 4; ++reg) {
        float p0 = 0.f, p1 = 0.f, pc = 0.f;
        #pragma unroll
        for (int t = 0; t < 4; ++t) {
            p0 = fmaf(hn_r[reg][t], aw0[t], p0);
            p1 = fmaf(hn_r[reg][t], aw1[t], p1);
            pc = fmaf(hn_r[reg][t], awc[t], pc);
        }
        sum0[reg] = row16_sum(p0);
        sum1[reg] = row16_sum(p1);
        sumc[reg] = row16_sum(pc);
    }
    if (c16 < 4) {   // lane c16==reg writes row quad*4+c16
        float A0 = (c16 == 0) ? sum0[0] : (c16 == 1) ? sum0[1]
                 : (c16 == 2) ? sum0[2] : sum0[3];
        float A1 = (c16 == 0) ? sum1[0] : (c16 == 1) ? sum1[1]
                 : (c16 == 2) ? sum1[2] : sum1[3];
        float C  = (c16 == 0) ? sumc[0] : (c16 == 1) ? sumc[1]
                 : (c16 == 2) ? sumc[2] : sumc[3];
        int gr = rowbase + R + quad * 4 + c16;
        oc[gr] = C + cb;
        A0 += ab0; A1 += ab1;
        float m = fmaxf(A0, A1);
        float e0 = __expf(A0 - m), e1 = __expf(A1 - m);
        float inv = 1.f / (e0 + e1);
        float2 pv; pv.x = e0 * inv; pv.y = e1 * inv;
        opi[gr] = pv;
    }
}

extern "C" void kernel_launch(void* const* d_in, const int* in_sizes, int n_in,
                              void* d_out, int out_size, void* d_ws, size_t ws_size,
                              hipStream_t stream) {
    const float* s        = (const float*)d_in[0];
    const float* h        = (const float*)d_in[1];
    const float* w_ih     = (const float*)d_in[2];
    const float* w_hh     = (const float*)d_in[3];
    const float* b_ih     = (const float*)d_in[4];
    const float* b_hh     = (const float*)d_in[5];
    const float* actor_w  = (const float*)d_in[6];
    const float* actor_b  = (const float*)d_in[7];
    const float* critic_w = (const float*)d_in[8];
    const float* critic_b = (const float*)d_in[9];
    float* out = (float*)d_out;

    int Btot = in_sizes[1] / 50;          // 262144
    int nTiles = Btot / 128;              // 2048 (exact)

    u32x4* ws = (u32x4*)d_ws;             // needs 1536*16 = 24576 B

    pack_w<<<6, 256, 0, stream>>>(w_ih, w_hh, b_ih, b_hh, ws);
    gru_fused<<<nTiles, BDIM, 0, stream>>>(s, h, w_ih, actor_w, actor_b,
                                           critic_w, critic_b, b_ih,
                                           (const u32x4*)ws, out, Btot, nTiles);
}